// Round 14
// baseline (151.027 us; speedup 1.0000x reference)
//
#include <hip/hip_runtime.h>
#include <stdint.h>

typedef uint32_t u32;
typedef uint64_t u64;

#define BN 16
#define CLS 80
#define ROWF 85
#define KSEL 512
#define NBKT 2048
#define TIE_CAP 4096
#define R1 64
#define CONF_T 0.001f
#define NMS_T 0.5f

__device__ __forceinline__ u32 flip_desc(float x) {
    u32 u = __float_as_uint(x);
    u32 m = (u & 0x80000000u) ? ~u : (u | 0x80000000u); // monotonic ascending
    return ~m;                                          // descending key
}
__device__ __forceinline__ float unflip(u32 key) {
    u32 m = ~key;
    u32 u = (m & 0x80000000u) ? (m & 0x7fffffffu) : ~m;
    return __uint_as_float(u);
}
__device__ __forceinline__ int conf_bucket(float cm) {
    float f = floorf(cm * 2048.0f);
    f = fminf(f, 2047.0f);
    f = fmaxf(f, 0.0f);
    return (int)f;
}

// ---------------- K1: keys only — pure streaming, no atomics, 7 blocks/CU ----------------
__global__ __launch_bounds__(256) void k1_keys(const float* __restrict__ pred,
                                               u32* __restrict__ keys, int totalRows) {
    __shared__ float stage[R1 * ROWF]; // 21,760 B
    int tid = threadIdx.x;
    int row0 = blockIdx.x * R1;
    int nrow = min(R1, totalRows - row0);
    int nf4 = nrow * ROWF / 4; // 64|48 rows * 85 -> /4 exact
    const float4* p4 = (const float4*)(pred + (long long)row0 * ROWF);
    float4* b4 = (float4*)stage;
    for (int k = tid; k < nf4; k += 256) b4[k] = p4[k];
    __syncthreads();
    int q = tid & 7;
    int base = tid & ~7;
    #pragma unroll
    for (int p = 0; p < 2; p++) {
        int r = (p << 5) + (tid >> 3); // 32 rows per pass, 8 lanes/row
        if (r < nrow) {
            const float* row = &stage[r * ROWF];
            float v0 = 0.0f;
            float mx = -3.402823466e+38f;
            bool fin = true;
            #pragma unroll
            for (int i = 0; i < 11; i++) {
                int e = q + (i << 3);
                if (e < ROWF) {
                    float v = row[e];
                    u32 bb = __float_as_uint(v);
                    if ((bb & 0x7f800000u) == 0x7f800000u) fin = false;
                    if (i == 0) v0 = v;
                    if (e >= 5) mx = fmaxf(mx, v); // max value only
                }
            }
            #pragma unroll
            for (int m = 4; m >= 1; m >>= 1) {
                mx = fmaxf(mx, __shfl_xor(mx, m));
                int ofin = __shfl_xor((int)fin, m);
                fin = fin && (ofin != 0);
            }
            float w   = __shfl(v0, base + 2);
            float h   = __shfl(v0, base + 3);
            float obj = __shfl(v0, base + 4);
            if (q == 0) {
                float conf = obj * mx;
                bool ok = (conf > CONF_T) && (w > 2.0f) && (w < 10000.0f) &&
                          (h > 2.0f) && (h < 10000.0f) && fin;
                keys[row0 + r] = flip_desc(ok ? conf : -1.0f);
            }
        }
    }
}

// ---- KMEGA: hist + threshold + compact + rank + gather + IoU + NMS + output, 1 block/image ----
__global__ __launch_bounds__(1024) void kmega(const float* __restrict__ pred,
                                              const u32* __restrict__ keys,
                                              u64* __restrict__ tiesG,
                                              float* __restrict__ out, int N) {
    int b = blockIdx.x;
    int tid = threadIdx.x;
    int lane = tid & 63;
    int wv = tid >> 6;
    const u32* kk = keys + (long long)b * N;

    // LDS union, phase-ordered aliasing (each region's prior tenant is dead before overwrite):
    // [0,16384):      {hist 8K | scan 4K | abvL 4K}  ->  S (gather output)
    // [16384,49152):  {tieL 32K}                     ->  MT (IoU output)
    // [49152,57344):  {BX4 8K}                       ->  MG (merge output)
    // [57344,58368):  TGT
    __shared__ __align__(16) unsigned char LDSU[58368];
    __shared__ u64 skey[KSEL]; // 4 KB, live across compact->gather boundary
    __shared__ u32 sh_Tb, sh_nA, sh_cA, sh_cT;
    __shared__ u64 sh_keep[8], sh_ok[8];
    u32* hist = (u32*)LDSU;
    u32* scan = (u32*)(LDSU + 8192);
    u64* abvL = (u64*)(LDSU + 12288);
    float* S  = (float*)LDSU;
    u64* tieL = (u64*)(LDSU + 16384);
    u64* MT   = (u64*)(LDSU + 16384);
    float4* BX4 = (float4*)(LDSU + 49152);
    float* MG = (float*)(LDSU + 49152);
    unsigned short* TGT = (unsigned short*)(LDSU + 57344);

    // ---- phase A1: value-space histogram ----
    for (int i = tid; i < NBKT; i += 1024) hist[i] = 0;
    if (tid == 0) { sh_cA = 0; sh_cT = 0; }
    __syncthreads();
    for (int i = tid; i < N; i += 1024)
        atomicAdd(&hist[conf_bucket(unflip(kk[i]))], 1u);
    __syncthreads();

    // ---- phase A2: threshold via suffix-from-top Hillis-Steele scan ----
    u32 h0 = hist[NBKT - 1 - 2 * tid];
    u32 h1 = hist[NBKT - 2 - 2 * tid];
    u32 s = h0 + h1;
    u32 v = s;
    for (int off = 1; off < 1024; off <<= 1) {
        scan[tid] = v;
        __syncthreads();
        u32 add = (tid >= off) ? scan[tid - off] : 0u;
        __syncthreads();
        v += add;
    }
    u32 excl = v - s;
    if (excl < KSEL && v >= KSEL) { // unique crossing thread
        if (excl + h0 >= KSEL) { sh_Tb = (u32)(NBKT - 1 - 2 * tid); sh_nA = excl; }
        else                   { sh_Tb = (u32)(NBKT - 2 - 2 * tid); sh_nA = excl + h0; }
    }
    __syncthreads();
    u32 Tb = sh_Tb, nA = sh_nA;
    u32 tsel = KSEL - nA;

    // ---- phase A3: compact to LDS lists (+ global tie mirror for overflow fallback) ----
    u64* tvG = tiesG + (long long)b * N;
    for (int i = tid; i < N; i += 1024) {
        u32 e = kk[i];
        u32 bk = (u32)conf_bucket(unflip(e));
        if (bk > Tb) {
            u32 p = atomicAdd(&sh_cA, 1u);
            abvL[p] = ((u64)e << 32) | (u32)i;
        } else if (bk == Tb) {
            u32 p = atomicAdd(&sh_cT, 1u);
            u64 ee = ((u64)e << 32) | (u32)i;
            if (p < TIE_CAP) tieL[p] = ee;
            tvG[p] = ee;
        }
    }
    __syncthreads();
    u32 ntie = sh_cT;
    bool lds_ties = (ntie <= TIE_CAP);

    // ---- phase A4: rank-place above (register-tile + readlane; u64 all distinct) ----
    {
        u64 e = (tid < (int)nA) ? abvL[tid] : ~0ull;
        u32 rnk = 0;
        for (int t = 0; t < 8; t++) {
            u32 kbase = (u32)t * 64u;
            if (kbase >= nA) break;
            u64 tval = abvL[kbase + lane];
            u32 tlo = (u32)tval, thi = (u32)(tval >> 32);
            int lim = min(64, (int)(nA - kbase));
            for (int m = 0; m < lim; m++) {
                u32 rl = __builtin_amdgcn_readlane(tlo, m);
                u32 rh = __builtin_amdgcn_readlane(thi, m);
                u64 ek = ((u64)rh << 32) | rl;
                rnk += (ek < e) ? 1u : 0u;
            }
        }
        if (tid < (int)nA) skey[rnk] = e;
    }
    // rank-place ties (always rank: deterministic, conf desc / idx asc)
    for (u32 jj = tid; jj < ntie; jj += 1024) {
        u64 e = lds_ties ? tieL[jj] : tvG[jj];
        u32 r = 0;
        if (lds_ties) { for (u32 k = 0; k < ntie; k++) r += (tieL[k] < e) ? 1u : 0u; }
        else          { for (u32 k = 0; k < ntie; k++) r += (tvG[k]  < e) ? 1u : 0u; }
        if (r < tsel) skey[nA + r] = e;
    }
    __syncthreads(); // hist/scan/abvL dead; tieL dead

    // ---- phase B: gather -> S; 8 lanes/row, 128 rows/round x 4, butterfly max/argmax ----
    {
        int q = tid & 7;
        int base = tid & ~7;
        #pragma unroll 1
        for (int p = 0; p < 4; p++) {
            int r = (p << 7) + (tid >> 3);
            int idx = (int)(skey[r] & 0xffffffffu);
            const float* row = pred + ((long long)b * N + idx) * ROWF;
            float v0 = 0.0f;
            float mx = -3.402823466e+38f; int am = 0;
            bool fin = true;
            #pragma unroll
            for (int i = 0; i < 11; i++) {
                int e = q + (i << 3);
                if (e < ROWF) {
                    float v = row[e];
                    u32 bb = __float_as_uint(v);
                    if ((bb & 0x7f800000u) == 0x7f800000u) fin = false;
                    if (i == 0) v0 = v;
                    if (e >= 5) { if (v > mx) { mx = v; am = e - 5; } } // strict >: first max
                }
            }
            #pragma unroll
            for (int m = 4; m >= 1; m >>= 1) {
                float omx = __shfl_xor(mx, m);
                int oam = __shfl_xor(am, m);
                int ofin = __shfl_xor((int)fin, m);
                if (omx > mx || (omx == mx && oam < am)) { mx = omx; am = oam; }
                fin = fin && (ofin != 0);
            }
            float cx = __shfl(v0, base + 0);
            float cy = __shfl(v0, base + 1);
            float w  = __shfl(v0, base + 2);
            float h  = __shfl(v0, base + 3);
            float obj= __shfl(v0, base + 4);
            if (q == 0) {
                float conf = obj * mx;
                bool ok = (conf > CONF_T) && (w > 2.0f) && (w < 10000.0f) &&
                          (h > 2.0f) && (h < 10000.0f) && fin;
                float off = (float)am * 10000.0f;
                float x1 = cx - w * 0.5f, y1 = cy - h * 0.5f;
                float x2 = cx + w * 0.5f, y2 = cy + h * 0.5f;
                float* sp = &S[r * 8];
                sp[0] = x1 + off; sp[1] = y1; sp[2] = x2 + off; sp[3] = y2;
                sp[4] = conf; sp[5] = mx; sp[6] = (float)am; sp[7] = ok ? 1.0f : 0.0f;
            }
        }
    }
    __syncthreads();

    // ---- phase C: IoU bitmatrix in LDS; 4 words/thread, wave-uniform j -> broadcasts ----
    if (tid < KSEL) BX4[tid] = *(const float4*)&S[tid * 8];
    __syncthreads();
    {
        int i = tid & (KSEL - 1);
        float4 bi = BX4[i];
        float x1 = bi.x, y1 = bi.y, x2 = bi.z, y2 = bi.w;
        float a1 = __fmul_rn(__fsub_rn(x2, x1), __fsub_rn(y2, y1));
        #pragma unroll 1
        for (int ww = 0; ww < 4; ww++) {
            int w = ww * 2 + (tid >> 9); // each (w,i) exactly once
            u64 bits = 0;
            int j0 = w * 64;
            #pragma unroll 4
            for (int jj = 0; jj < 64; jj++) {
                float4 bj = BX4[j0 + jj];
                float ix = fmaxf(__fsub_rn(fminf(x2, bj.z), fmaxf(x1, bj.x)), 0.0f);
                float iy = fmaxf(__fsub_rn(fminf(y2, bj.w), fmaxf(y1, bj.y)), 0.0f);
                float inter = __fmul_rn(ix, iy);
                float a2 = __fmul_rn(__fsub_rn(bj.z, bj.x), __fsub_rn(bj.w, bj.y));
                float denom = __fadd_rn(__fsub_rn(__fadd_rn(a1, a2), inter), 1e-9f);
                float iou = __fdiv_rn(inter, denom);
                if (iou > NMS_T) bits |= (1ull << jj);
            }
            MT[w * KSEL + i] = bits;
        }
    }
    __syncthreads(); // BX4 dead after this phase's reads complete (barrier) -> MG may overwrite

    // ---- phase D: chunked scalar keep-scan (wave 0) ----
    if (wv == 0) {
        u32 a_bits = 0; // bit w = column (w*64+lane) alive
        #pragma unroll
        for (int w = 0; w < 8; w++)
            if (S[(w * 64 + lane) * 8 + 7] > 0.5f) a_bits |= 1u << w;
        #pragma unroll
        for (int w = 0; w < 8; w++) {
            u64 ow = __ballot((a_bits >> w) & 1u);
            if (lane == 0) sh_ok[w] = ow;
        }
        #pragma unroll 1
        for (int c = 0; c < 8; c++) {
            u64 cross[8];
            #pragma unroll
            for (int w = 0; w < 8; w++) cross[w] = MT[c * KSEL + w * 64 + lane];
            u64 intra = MT[c * KSEL + c * 64 + lane];
            u64 aliveC = __ballot((a_bits >> c) & 1u);
            u32 ilo = (u32)intra, ihi = (u32)(intra >> 32);
            u64 keptC = 0;
            #pragma unroll
            for (int m = 0; m < 64; m++) { // symmetric: row m == lane m's column word
                u32 rl = __builtin_amdgcn_readlane(ilo, m);
                u32 rh = __builtin_amdgcn_readlane(ihi, m);
                u64 rowm = ((u64)rh << 32) | rl;
                u64 take = (aliveC >> m) & 1ull;
                u64 msk = (u64)0 - take;
                keptC |= take << m;
                aliveC &= ~(rowm & msk);
            }
            if (lane == 0) sh_keep[c] = keptC;
            #pragma unroll
            for (int w = 0; w < 8; w++)
                if (cross[w] & keptC) a_bits &= ~(1u << w);
        }
    }
    __syncthreads();
    u64 keepW[8], okW[8];
    #pragma unroll
    for (int w = 0; w < 8; w++) { keepW[w] = sh_keep[w]; okW[w] = sh_ok[w]; }

    // ---- phase E1: merge target per column (M symmetric) ----
    for (int j = tid; j < KSEL; j += 1024) {
        int r = j >> 6, ln = j & 63;
        int tgt = 0xffff;
        if ((okW[r] >> ln) & 1ull) {
            #pragma unroll
            for (int w = 7; w >= 0; w--) {
                u64 m = MT[w * KSEL + j] & keepW[w];
                if (m) tgt = w * 64 + (int)__builtin_ctzll(m);
            }
        }
        TGT[j] = (unsigned short)tgt;
    }
    __syncthreads();

    // ---- phase E2: weighted merge per kept row, ascending-j order ----
    for (int k = tid; k < KSEL; k += 1024) {
        int r = k >> 6, ln = k & 63;
        if ((keepW[r] >> ln) & 1ull) {
            float s0 = 0.f, s1 = 0.f, s2 = 0.f, s3 = 0.f, sw = 0.f;
            #pragma unroll 1
            for (int w = 0; w < 8; w++) {
                u64 m = MT[w * KSEL + k] & okW[w];
                while (m) {
                    int j = w * 64 + (int)__builtin_ctzll(m);
                    m &= m - 1;
                    if (TGT[j] == (unsigned short)k) {
                        float c = S[j * 8 + 4];
                        s0 += c * S[j * 8 + 0]; s1 += c * S[j * 8 + 1];
                        s2 += c * S[j * 8 + 2]; s3 += c * S[j * 8 + 3];
                        sw += c;
                    }
                }
            }
            float d = sw + 1e-12f;
            MG[k * 4 + 0] = s0 / d; MG[k * 4 + 1] = s1 / d;
            MG[k * 4 + 2] = s2 / d; MG[k * 4 + 3] = s3 / d;
        }
    }
    __syncthreads();

    // ---- output: compact kept rows in order, zero tail ----
    int nk = 0;
    #pragma unroll
    for (int w = 0; w < 8; w++) nk += __popcll(keepW[w]);
    float* ob = out + (long long)b * KSEL * 7;
    for (int i = tid; i < KSEL; i += 1024) {
        int wi = i >> 6, bi = i & 63;
        if ((keepW[wi] >> bi) & 1ull) {
            int rank = 0;
            for (int w = 0; w < wi; w++) rank += __popcll(keepW[w]);
            rank += __popcll(keepW[wi] & ((1ull << bi) - 1ull));
            float off = S[i * 8 + 6] * 10000.0f;
            float* o = ob + rank * 7;
            o[0] = MG[i * 4 + 0] - off; o[1] = MG[i * 4 + 1];
            o[2] = MG[i * 4 + 2] - off; o[3] = MG[i * 4 + 3];
            o[4] = S[i * 8 + 4]; o[5] = S[i * 8 + 5]; o[6] = S[i * 8 + 6];
        }
    }
    for (int p = nk + tid; p < KSEL; p += 1024) {
        float* o = ob + p * 7;
        #pragma unroll
        for (int c = 0; c < 7; c++) o[c] = 0.0f;
    }
}

extern "C" void kernel_launch(void* const* d_in, const int* in_sizes, int n_in,
                              void* d_out, int out_size, void* d_ws, size_t ws_size,
                              hipStream_t stream) {
    const float* pred = (const float*)d_in[0];
    float* out = (float*)d_out;
    int total = in_sizes[0];
    int N = total / (BN * ROWF); // 22743
    int totalRows = BN * N;

    char* ws = (char*)d_ws;
    size_t o = 0;
    u32* keys = (u32*)(ws + o);  o += (size_t)totalRows * 4;
    u64* tiesG = (u64*)(ws + o); o += (size_t)BN * N * 8;
    (void)ws_size;

    k1_keys<<<(totalRows + R1 - 1) / R1, 256, 0, stream>>>(pred, keys, totalRows);
    kmega<<<BN, 1024, 0, stream>>>(pred, keys, tiesG, out, N);
}

// Round 15
// 87.483 us; speedup vs baseline: 1.7264x; 1.7264x over previous
//
#include <hip/hip_runtime.h>
#include <stdint.h>

typedef uint32_t u32;
typedef uint64_t u64;

#define BN 16
#define CLS 80
#define ROWF 85
#define KSEL 512
#define NBKT 2048
#define TIE_CAP 4096
#define R1 64
#define CONF_T 0.001f
#define NMS_T 0.5f

__device__ __forceinline__ u32 flip_desc(float x) {
    u32 u = __float_as_uint(x);
    u32 m = (u & 0x80000000u) ? ~u : (u | 0x80000000u); // monotonic ascending
    return ~m;                                          // descending key
}
__device__ __forceinline__ float unflip(u32 key) {
    u32 m = ~key;
    u32 u = (m & 0x80000000u) ? (m & 0x7fffffffu) : ~m;
    return __uint_as_float(u);
}
__device__ __forceinline__ int conf_bucket(float cm) {
    float f = floorf(cm * 2048.0f);
    f = fminf(f, 2047.0f);
    f = fmaxf(f, 0.0f);
    return (int)f;
}

// ---------------- K1: keys only — pure streaming, no atomics, 7 blocks/CU ----------------
__global__ __launch_bounds__(256) void k1_keys(const float* __restrict__ pred,
                                               u32* __restrict__ keys, int totalRows) {
    __shared__ float stage[R1 * ROWF]; // 21,760 B
    int tid = threadIdx.x;
    int row0 = blockIdx.x * R1;
    int nrow = min(R1, totalRows - row0);
    int nf4 = nrow * ROWF / 4; // 64|48 rows * 85 -> /4 exact
    const float4* p4 = (const float4*)(pred + (long long)row0 * ROWF);
    float4* b4 = (float4*)stage;
    for (int k = tid; k < nf4; k += 256) b4[k] = p4[k];
    __syncthreads();
    int q = tid & 7;
    int base = tid & ~7;
    #pragma unroll
    for (int p = 0; p < 2; p++) {
        int r = (p << 5) + (tid >> 3); // 32 rows per pass, 8 lanes/row
        if (r < nrow) {
            const float* row = &stage[r * ROWF];
            float v0 = 0.0f;
            float mx = -3.402823466e+38f;
            bool fin = true;
            #pragma unroll
            for (int i = 0; i < 11; i++) {
                int e = q + (i << 3);
                if (e < ROWF) {
                    float v = row[e];
                    u32 bb = __float_as_uint(v);
                    if ((bb & 0x7f800000u) == 0x7f800000u) fin = false;
                    if (i == 0) v0 = v;
                    if (e >= 5) mx = fmaxf(mx, v); // max value only
                }
            }
            #pragma unroll
            for (int m = 4; m >= 1; m >>= 1) {
                mx = fmaxf(mx, __shfl_xor(mx, m));
                int ofin = __shfl_xor((int)fin, m);
                fin = fin && (ofin != 0);
            }
            float w   = __shfl(v0, base + 2);
            float h   = __shfl(v0, base + 3);
            float obj = __shfl(v0, base + 4);
            if (q == 0) {
                float conf = obj * mx;
                bool ok = (conf > CONF_T) && (w > 2.0f) && (w < 10000.0f) &&
                          (h > 2.0f) && (h < 10000.0f) && fin;
                keys[row0 + r] = flip_desc(ok ? conf : -1.0f);
            }
        }
    }
}

// ---------------- KM: per-image hist + threshold + compact + rank + gather (LDS-fused) ----------------
__global__ __launch_bounds__(1024) void kM(const float* __restrict__ pred,
                                           const u32* __restrict__ keys,
                                           u64* __restrict__ tiesG,
                                           float* __restrict__ sel, int N) {
    int b = blockIdx.x;
    int tid = threadIdx.x;
    int lane = tid & 63;
    int wv = tid >> 6;
    const u32* kk = keys + (long long)b * N;
    __shared__ u32 hist[NBKT];    // 8 KB
    __shared__ u32 scan[1024];    // 4 KB
    __shared__ u64 abvL[KSEL];    // 4 KB
    __shared__ u64 skey[KSEL];    // 4 KB
    __shared__ u64 tieL[TIE_CAP]; // 32 KB
    __shared__ u32 sh_Tb, sh_nA, sh_cA, sh_cT;

    // ---- A1: value-space histogram ----
    for (int i = tid; i < NBKT; i += 1024) hist[i] = 0;
    if (tid == 0) { sh_cA = 0; sh_cT = 0; }
    __syncthreads();
    for (int i = tid; i < N; i += 1024)
        atomicAdd(&hist[conf_bucket(unflip(kk[i]))], 1u);
    __syncthreads();

    // ---- A2: threshold via shuffle wave-scan (2 barriers total) ----
    u32 h0 = hist[NBKT - 1 - 2 * tid];
    u32 h1 = hist[NBKT - 2 - 2 * tid];
    u32 s = h0 + h1;
    u32 v = s;
    #pragma unroll
    for (int off = 1; off < 64; off <<= 1) {
        u32 n = __shfl_up(v, off);
        if (lane >= off) v += n;
    }
    if (lane == 63) scan[wv] = v; // wave total
    __syncthreads();
    if (wv == 0 && lane < 16) {
        u32 t = scan[lane];
        u32 p = t;
        #pragma unroll
        for (int off = 1; off < 16; off <<= 1) {
            u32 n = __shfl_up(p, off);
            if (lane >= off) p += n;
        }
        scan[16 + lane] = p - t; // exclusive prefix per wave
    }
    __syncthreads();
    v += scan[16 + wv];
    u32 excl = v - s;
    if (excl < KSEL && v >= KSEL) { // unique crossing thread
        if (excl + h0 >= KSEL) { sh_Tb = (u32)(NBKT - 1 - 2 * tid); sh_nA = excl; }
        else                   { sh_Tb = (u32)(NBKT - 2 - 2 * tid); sh_nA = excl + h0; }
    }
    __syncthreads();
    u32 Tb = sh_Tb, nA = sh_nA;
    u32 tsel = KSEL - nA;

    // ---- A3: compact to LDS lists (+ global tie mirror for overflow fallback) ----
    u64* tvG = tiesG + (long long)b * N;
    for (int i = tid; i < N; i += 1024) {
        u32 e = kk[i];
        u32 bk = (u32)conf_bucket(unflip(e));
        if (bk > Tb) {
            u32 p = atomicAdd(&sh_cA, 1u);
            abvL[p] = ((u64)e << 32) | (u32)i;
        } else if (bk == Tb) {
            u32 p = atomicAdd(&sh_cT, 1u);
            u64 ee = ((u64)e << 32) | (u32)i;
            if (p < TIE_CAP) tieL[p] = ee;
            tvG[p] = ee;
        }
    }
    __syncthreads();
    u32 ntie = sh_cT;
    bool lds_ties = (ntie <= TIE_CAP);

    // ---- A4: broadcast-rank above (thread t: element tid&511, half tid>>9) ----
    {
        int e_id = tid & 511;
        u32 half = (u32)(tid >> 9);
        u64 e_val = (e_id < (int)nA) ? abvL[e_id] : ~0ull;
        u32 hsz = (nA + 1) >> 1;
        u32 kk0 = half * hsz;
        u32 kk1 = min(nA, kk0 + hsz);
        u32 cnt = 0;
        for (u32 k = kk0; k < kk1; k++)          // wave-uniform k -> LDS broadcast
            cnt += (abvL[k] < e_val) ? 1u : 0u;  // all u64 distinct (low32 unique idx)
        scan[tid] = cnt;
        __syncthreads();
        if (tid < (int)nA) {
            u32 rnk = scan[tid] + scan[tid + 512];
            skey[rnk] = abvL[tid];
        }
    }
    // rank-place ties (always rank: deterministic, conf desc / idx asc)
    for (u32 jj = tid; jj < ntie; jj += 1024) {
        u64 e = lds_ties ? tieL[jj] : tvG[jj];
        u32 r = 0;
        if (lds_ties) { for (u32 k = 0; k < ntie; k++) r += (tieL[k] < e) ? 1u : 0u; }
        else          { for (u32 k = 0; k < ntie; k++) r += (tvG[k]  < e) ? 1u : 0u; }
        if (r < tsel) skey[nA + r] = e; // asc u64 == conf desc, idx asc == lax.top_k
    }
    __syncthreads();

    // ---- B: gather -> sel; 8 lanes/row, 128 rows/round x 4, butterfly max/argmax ----
    {
        int q = tid & 7;
        int base = tid & ~7;
        #pragma unroll 1
        for (int p = 0; p < 4; p++) {
            int r = (p << 7) + (tid >> 3);
            int idx = (int)(skey[r] & 0xffffffffu);
            const float* row = pred + ((long long)b * N + idx) * ROWF;
            float v0 = 0.0f;
            float mx = -3.402823466e+38f; int am = 0;
            bool fin = true;
            #pragma unroll
            for (int i = 0; i < 11; i++) {
                int e = q + (i << 3); // consecutive lanes read consecutive dwords
                if (e < ROWF) {
                    float v = row[e];
                    u32 bb = __float_as_uint(v);
                    if ((bb & 0x7f800000u) == 0x7f800000u) fin = false;
                    if (i == 0) v0 = v;
                    if (e >= 5) { if (v > mx) { mx = v; am = e - 5; } } // strict >: first max
                }
            }
            // combine: larger val wins; on equal val, smaller class idx (== first occurrence)
            #pragma unroll
            for (int m = 4; m >= 1; m >>= 1) {
                float omx = __shfl_xor(mx, m);
                int oam = __shfl_xor(am, m);
                int ofin = __shfl_xor((int)fin, m);
                if (omx > mx || (omx == mx && oam < am)) { mx = omx; am = oam; }
                fin = fin && (ofin != 0);
            }
            float cx = __shfl(v0, base + 0);
            float cy = __shfl(v0, base + 1);
            float w  = __shfl(v0, base + 2);
            float h  = __shfl(v0, base + 3);
            float obj= __shfl(v0, base + 4);
            if (q == 0) {
                float conf = obj * mx;
                bool ok = (conf > CONF_T) && (w > 2.0f) && (w < 10000.0f) &&
                          (h > 2.0f) && (h < 10000.0f) && fin;
                float off = (float)am * 10000.0f;
                float x1 = cx - w * 0.5f, y1 = cy - h * 0.5f;
                float x2 = cx + w * 0.5f, y2 = cy + h * 0.5f;
                float* sp = sel + ((long long)b * KSEL + r) * 8;
                sp[0] = x1 + off; sp[1] = y1; sp[2] = x2 + off; sp[3] = y2;
                sp[4] = conf; sp[5] = mx; sp[6] = (float)am; sp[7] = ok ? 1.0f : 0.0f;
            }
        }
    }
}

// ---------------- K4: 512x512 iou>thres bitmatrix, TRANSPOSED [b][w][i], 256 blocks ----------------
__global__ __launch_bounds__(256) void k4_iou(const float* __restrict__ sel, u64* __restrict__ matT) {
    int b = blockIdx.x >> 4;
    int t = ((blockIdx.x & 15) << 8) + threadIdx.x;
    int w = t >> 9;             // uniform per block
    int i = t & (KSEL - 1);
    __shared__ float BX[KSEL * 4]; // 8KB
    const float4* S4 = (const float4*)(sel + (long long)b * KSEL * 8);
    float4* B4 = (float4*)BX;
    for (int j = threadIdx.x; j < KSEL; j += 256) B4[j] = S4[j * 2];
    __syncthreads();
    float x1 = BX[i * 4 + 0], y1 = BX[i * 4 + 1], x2 = BX[i * 4 + 2], y2 = BX[i * 4 + 3];
    float a1 = __fmul_rn(__fsub_rn(x2, x1), __fsub_rn(y2, y1));
    u64 bits = 0;
    int j0 = w * 64;
    const float4* BB = (const float4*)BX;
    for (int jj = 0; jj < 64; jj++) {
        float4 bj = BB[j0 + jj]; // broadcast: block shares w
        float ix = fmaxf(__fsub_rn(fminf(x2, bj.z), fmaxf(x1, bj.x)), 0.0f);
        float iy = fmaxf(__fsub_rn(fminf(y2, bj.w), fmaxf(y1, bj.y)), 0.0f);
        float inter = __fmul_rn(ix, iy);
        float a2 = __fmul_rn(__fsub_rn(bj.z, bj.x), __fsub_rn(bj.w, bj.y));
        float denom = __fadd_rn(__fsub_rn(__fadd_rn(a1, a2), inter), 1e-9f);
        float iou = __fdiv_rn(inter, denom);
        if (iou > NMS_T) bits |= (1ull << jj);
    }
    matT[((long long)b * 8 + w) * KSEL + i] = bits; // coalesced
}

// ---------------- K5: chunked scalar keep-scan + parallel merge + output (1024 thr) ----------------
__global__ __launch_bounds__(1024) void k5_nms(const float* __restrict__ sel,
                                               const u64* __restrict__ matT,
                                               float* __restrict__ out) {
    int b = blockIdx.x;
    int tid = threadIdx.x;
    int lane = tid & 63;
    int wv = tid >> 6;
    __shared__ float S[KSEL * 8];        // 16KB
    __shared__ u64 MT[8 * KSEL];         // 32KB, [w][i]
    __shared__ float MG[KSEL * 4];       // 8KB
    __shared__ unsigned short TGT[KSEL]; // 1KB
    __shared__ u64 sh_keep[8], sh_ok[8];
    const float4* gs = (const float4*)(sel + (long long)b * KSEL * 8);
    float4* s4 = (float4*)S;
    for (int i = tid; i < KSEL * 2; i += 1024) s4[i] = gs[i];
    const ulonglong2* gm2 = (const ulonglong2*)(matT + (long long)b * 8 * KSEL);
    ulonglong2* m2 = (ulonglong2*)MT;
    for (int i = tid; i < 4 * KSEL; i += 1024) m2[i] = gm2[i];
    __syncthreads();

    if (wv == 0) {
        u32 a_bits = 0; // bit w = column (w*64+lane) alive
        #pragma unroll
        for (int w = 0; w < 8; w++)
            if (S[(w * 64 + lane) * 8 + 7] > 0.5f) a_bits |= 1u << w;
        #pragma unroll
        for (int w = 0; w < 8; w++) {
            u64 ow = __ballot((a_bits >> w) & 1u);
            if (lane == 0) sh_ok[w] = ow;
        }
        #pragma unroll 1
        for (int c = 0; c < 8; c++) {
            u64 cross[8];
            #pragma unroll
            for (int w = 0; w < 8; w++) cross[w] = MT[c * KSEL + w * 64 + lane];
            u64 intra = MT[c * KSEL + c * 64 + lane];
            u64 aliveC = __ballot((a_bits >> c) & 1u);
            u32 ilo = (u32)intra, ihi = (u32)(intra >> 32);
            u64 keptC = 0;
            #pragma unroll
            for (int m = 0; m < 64; m++) { // symmetric: row m == lane m's column word
                u32 rl = __builtin_amdgcn_readlane(ilo, m);
                u32 rh = __builtin_amdgcn_readlane(ihi, m);
                u64 rowm = ((u64)rh << 32) | rl;
                u64 take = (aliveC >> m) & 1ull;
                u64 msk = (u64)0 - take;
                keptC |= take << m;
                aliveC &= ~(rowm & msk);
            }
            if (lane == 0) sh_keep[c] = keptC;
            #pragma unroll
            for (int w = 0; w < 8; w++)
                if (cross[w] & keptC) a_bits &= ~(1u << w);
        }
    }
    __syncthreads();
    u64 keepW[8], okW[8];
    #pragma unroll
    for (int w = 0; w < 8; w++) { keepW[w] = sh_keep[w]; okW[w] = sh_ok[w]; }

    // merge target per column (M symmetric)
    for (int j = tid; j < KSEL; j += 1024) {
        int r = j >> 6, ln = j & 63;
        int tgt = 0xffff;
        if ((okW[r] >> ln) & 1ull) {
            #pragma unroll
            for (int w = 7; w >= 0; w--) {
                u64 m = MT[w * KSEL + j] & keepW[w];
                if (m) tgt = w * 64 + (int)__builtin_ctzll(m);
            }
        }
        TGT[j] = (unsigned short)tgt;
    }
    __syncthreads();

    // weighted merge per kept row, ascending-j order
    for (int k = tid; k < KSEL; k += 1024) {
        int r = k >> 6, ln = k & 63;
        if ((keepW[r] >> ln) & 1ull) {
            float s0 = 0.f, s1 = 0.f, s2 = 0.f, s3 = 0.f, sw = 0.f;
            #pragma unroll 1
            for (int w = 0; w < 8; w++) {
                u64 m = MT[w * KSEL + k] & okW[w];
                while (m) {
                    int j = w * 64 + (int)__builtin_ctzll(m);
                    m &= m - 1;
                    if (TGT[j] == (unsigned short)k) {
                        float c = S[j * 8 + 4];
                        s0 += c * S[j * 8 + 0]; s1 += c * S[j * 8 + 1];
                        s2 += c * S[j * 8 + 2]; s3 += c * S[j * 8 + 3];
                        sw += c;
                    }
                }
            }
            float d = sw + 1e-12f;
            MG[k * 4 + 0] = s0 / d; MG[k * 4 + 1] = s1 / d;
            MG[k * 4 + 2] = s2 / d; MG[k * 4 + 3] = s3 / d;
        }
    }
    __syncthreads();

    // output: compact kept rows in order, zero tail
    int nk = 0;
    #pragma unroll
    for (int w = 0; w < 8; w++) nk += __popcll(keepW[w]);
    float* ob = out + (long long)b * KSEL * 7;
    for (int i = tid; i < KSEL; i += 1024) {
        int wi = i >> 6, bi = i & 63;
        if ((keepW[wi] >> bi) & 1ull) {
            int rank = 0;
            for (int w = 0; w < wi; w++) rank += __popcll(keepW[w]);
            rank += __popcll(keepW[wi] & ((1ull << bi) - 1ull));
            float off = S[i * 8 + 6] * 10000.0f;
            float* o = ob + rank * 7;
            o[0] = MG[i * 4 + 0] - off; o[1] = MG[i * 4 + 1];
            o[2] = MG[i * 4 + 2] - off; o[3] = MG[i * 4 + 3];
            o[4] = S[i * 8 + 4]; o[5] = S[i * 8 + 5]; o[6] = S[i * 8 + 6];
        }
    }
    for (int p = nk + tid; p < KSEL; p += 1024) {
        float* o = ob + p * 7;
        #pragma unroll
        for (int c = 0; c < 7; c++) o[c] = 0.0f;
    }
}

extern "C" void kernel_launch(void* const* d_in, const int* in_sizes, int n_in,
                              void* d_out, int out_size, void* d_ws, size_t ws_size,
                              hipStream_t stream) {
    const float* pred = (const float*)d_in[0];
    float* out = (float*)d_out;
    int total = in_sizes[0];
    int N = total / (BN * ROWF); // 22743
    int totalRows = BN * N;

    char* ws = (char*)d_ws;
    size_t o = 0;
    u32* keys = (u32*)(ws + o);    o += (size_t)totalRows * 4;
    float* sel = (float*)(ws + o); o += (size_t)BN * KSEL * 8 * 4;
    u64* matT = (u64*)(ws + o);    o += (size_t)BN * KSEL * 8 * 8;
    u64* tiesG = (u64*)(ws + o);   o += (size_t)BN * N * 8;
    (void)ws_size;

    k1_keys<<<(totalRows + R1 - 1) / R1, 256, 0, stream>>>(pred, keys, totalRows);
    kM<<<BN, 1024, 0, stream>>>(pred, keys, tiesG, sel, N);
    k4_iou<<<BN * 16, 256, 0, stream>>>(sel, matT);
    k5_nms<<<BN, 1024, 0, stream>>>(sel, matT, out);
}

// Round 16
// 83.960 us; speedup vs baseline: 1.7988x; 1.0420x over previous
//
#include <hip/hip_runtime.h>
#include <stdint.h>

typedef uint32_t u32;
typedef uint64_t u64;

#define BN 16
#define CLS 80
#define ROWF 85
#define KSEL 512
#define NBKT 2048
#define TIE_CAP 4096
#define CONF_T 0.001f
#define NMS_T 0.5f

__device__ __forceinline__ u32 flip_desc(float x) {
    u32 u = __float_as_uint(x);
    u32 m = (u & 0x80000000u) ? ~u : (u | 0x80000000u); // monotonic ascending
    return ~m;                                          // descending key
}
__device__ __forceinline__ float unflip(u32 key) {
    u32 m = ~key;
    u32 u = (m & 0x80000000u) ? (m & 0x7fffffffu) : ~m;
    return __uint_as_float(u);
}
__device__ __forceinline__ int conf_bucket(float cm) {
    float f = floorf(cm * 2048.0f);
    f = fminf(f, 2047.0f);
    f = fmaxf(f, 0.0f);
    return (int)f;
}

// ---------------- K1: keys — DIRECT global reads, no LDS, no barrier ----------------
// 512 threads = 64 groups x 8 lanes; 128 rows/block in 2 passes. Each lane issues 11
// independent loads (row elems q, q+8, ...) -> deep pipelining; L1 merges quarter-lines.
__global__ __launch_bounds__(512) void k1_keys(const float* __restrict__ pred,
                                               u32* __restrict__ keys, int totalRows) {
    int tid = threadIdx.x;
    int row0 = blockIdx.x * 128;
    int q = tid & 7;
    int base = tid & ~7;
    #pragma unroll
    for (int p = 0; p < 2; p++) {
        int r = row0 + (p << 6) + (tid >> 3);
        if (r < totalRows) {
            const float* row = pred + (long long)r * ROWF;
            float v0 = 0.0f;
            float mx = -3.402823466e+38f;
            bool fin = true;
            #pragma unroll
            for (int i = 0; i < 11; i++) {
                int e = q + (i << 3);
                if (e < ROWF) {
                    float v = row[e];
                    u32 bb = __float_as_uint(v);
                    if ((bb & 0x7f800000u) == 0x7f800000u) fin = false;
                    if (i == 0) v0 = v;
                    if (e >= 5) mx = fmaxf(mx, v); // max value only
                }
            }
            #pragma unroll
            for (int m = 4; m >= 1; m >>= 1) {
                mx = fmaxf(mx, __shfl_xor(mx, m));
                int ofin = __shfl_xor((int)fin, m);
                fin = fin && (ofin != 0);
            }
            float w   = __shfl(v0, base + 2);
            float h   = __shfl(v0, base + 3);
            float obj = __shfl(v0, base + 4);
            if (q == 0) {
                float conf = obj * mx;
                bool ok = (conf > CONF_T) && (w > 2.0f) && (w < 10000.0f) &&
                          (h > 2.0f) && (h < 10000.0f) && fin;
                keys[r] = flip_desc(ok ? conf : -1.0f);
            }
        }
    }
}

// ---------------- KM: per-image hist + threshold + compact + rank + gather (LDS-fused) ----------------
__global__ __launch_bounds__(1024) void kM(const float* __restrict__ pred,
                                           const u32* __restrict__ keys,
                                           u64* __restrict__ tiesG,
                                           float* __restrict__ sel, int N) {
    int b = blockIdx.x;
    int tid = threadIdx.x;
    int lane = tid & 63;
    int wv = tid >> 6;
    const u32* kk = keys + (long long)b * N;
    __shared__ u32 hist[NBKT];    // 8 KB
    __shared__ u32 scan[1024];    // 4 KB
    __shared__ u64 abvL[KSEL];    // 4 KB
    __shared__ u64 skey[KSEL];    // 4 KB
    __shared__ u64 tieL[TIE_CAP]; // 32 KB
    __shared__ u32 sh_Tb, sh_nA, sh_cA, sh_cT;

    // ---- A1: value-space histogram ----
    for (int i = tid; i < NBKT; i += 1024) hist[i] = 0;
    if (tid == 0) { sh_cA = 0; sh_cT = 0; }
    __syncthreads();
    #pragma unroll 4
    for (int i = tid; i < N; i += 1024)
        atomicAdd(&hist[conf_bucket(unflip(kk[i]))], 1u);
    __syncthreads();

    // ---- A2: threshold via shuffle wave-scan (2 barriers total) ----
    u32 h0 = hist[NBKT - 1 - 2 * tid];
    u32 h1 = hist[NBKT - 2 - 2 * tid];
    u32 s = h0 + h1;
    u32 v = s;
    #pragma unroll
    for (int off = 1; off < 64; off <<= 1) {
        u32 n = __shfl_up(v, off);
        if (lane >= off) v += n;
    }
    if (lane == 63) scan[wv] = v; // wave total
    __syncthreads();
    if (wv == 0 && lane < 16) {
        u32 t = scan[lane];
        u32 p = t;
        #pragma unroll
        for (int off = 1; off < 16; off <<= 1) {
            u32 n = __shfl_up(p, off);
            if (lane >= off) p += n;
        }
        scan[16 + lane] = p - t; // exclusive prefix per wave
    }
    __syncthreads();
    v += scan[16 + wv];
    u32 excl = v - s;
    if (excl < KSEL && v >= KSEL) { // unique crossing thread
        if (excl + h0 >= KSEL) { sh_Tb = (u32)(NBKT - 1 - 2 * tid); sh_nA = excl; }
        else                   { sh_Tb = (u32)(NBKT - 2 - 2 * tid); sh_nA = excl + h0; }
    }
    __syncthreads();
    u32 Tb = sh_Tb, nA = sh_nA;
    u32 tsel = KSEL - nA;

    // ---- A3: compact to LDS lists (+ global tie mirror for overflow fallback) ----
    u64* tvG = tiesG + (long long)b * N;
    #pragma unroll 4
    for (int i = tid; i < N; i += 1024) {
        u32 e = kk[i];
        u32 bk = (u32)conf_bucket(unflip(e));
        if (bk > Tb) {
            u32 p = atomicAdd(&sh_cA, 1u);
            abvL[p] = ((u64)e << 32) | (u32)i;
        } else if (bk == Tb) {
            u32 p = atomicAdd(&sh_cT, 1u);
            u64 ee = ((u64)e << 32) | (u32)i;
            if (p < TIE_CAP) tieL[p] = ee;
            tvG[p] = ee;
        }
    }
    __syncthreads();
    u32 ntie = sh_cT;
    bool lds_ties = (ntie <= TIE_CAP);

    // ---- A4: broadcast-rank above (thread t: element tid&511, half tid>>9) ----
    {
        int e_id = tid & 511;
        u32 half = (u32)(tid >> 9);
        u64 e_val = (e_id < (int)nA) ? abvL[e_id] : ~0ull;
        u32 hsz = (nA + 1) >> 1;
        u32 kk0 = half * hsz;
        u32 kk1 = min(nA, kk0 + hsz);
        u32 cnt = 0;
        for (u32 k = kk0; k < kk1; k++)          // wave-uniform k -> LDS broadcast
            cnt += (abvL[k] < e_val) ? 1u : 0u;  // all u64 distinct (low32 unique idx)
        scan[tid] = cnt;
        __syncthreads();
        if (tid < (int)nA) {
            u32 rnk = scan[tid] + scan[tid + 512];
            skey[rnk] = abvL[tid];
        }
    }
    // rank-place ties (always rank: deterministic, conf desc / idx asc)
    for (u32 jj = tid; jj < ntie; jj += 1024) {
        u64 e = lds_ties ? tieL[jj] : tvG[jj];
        u32 r = 0;
        if (lds_ties) { for (u32 k = 0; k < ntie; k++) r += (tieL[k] < e) ? 1u : 0u; }
        else          { for (u32 k = 0; k < ntie; k++) r += (tvG[k]  < e) ? 1u : 0u; }
        if (r < tsel) skey[nA + r] = e; // asc u64 == conf desc, idx asc == lax.top_k
    }
    __syncthreads();

    // ---- B: gather -> sel; 8 lanes/row, 128 rows/round x 4, butterfly max/argmax ----
    {
        int q = tid & 7;
        int base = tid & ~7;
        #pragma unroll 1
        for (int p = 0; p < 4; p++) {
            int r = (p << 7) + (tid >> 3);
            int idx = (int)(skey[r] & 0xffffffffu);
            const float* row = pred + ((long long)b * N + idx) * ROWF;
            float v0 = 0.0f;
            float mx = -3.402823466e+38f; int am = 0;
            bool fin = true;
            #pragma unroll
            for (int i = 0; i < 11; i++) {
                int e = q + (i << 3); // consecutive lanes read consecutive dwords
                if (e < ROWF) {
                    float v = row[e];
                    u32 bb = __float_as_uint(v);
                    if ((bb & 0x7f800000u) == 0x7f800000u) fin = false;
                    if (i == 0) v0 = v;
                    if (e >= 5) { if (v > mx) { mx = v; am = e - 5; } } // strict >: first max
                }
            }
            // combine: larger val wins; on equal val, smaller class idx (== first occurrence)
            #pragma unroll
            for (int m = 4; m >= 1; m >>= 1) {
                float omx = __shfl_xor(mx, m);
                int oam = __shfl_xor(am, m);
                int ofin = __shfl_xor((int)fin, m);
                if (omx > mx || (omx == mx && oam < am)) { mx = omx; am = oam; }
                fin = fin && (ofin != 0);
            }
            float cx = __shfl(v0, base + 0);
            float cy = __shfl(v0, base + 1);
            float w  = __shfl(v0, base + 2);
            float h  = __shfl(v0, base + 3);
            float obj= __shfl(v0, base + 4);
            if (q == 0) {
                float conf = obj * mx;
                bool ok = (conf > CONF_T) && (w > 2.0f) && (w < 10000.0f) &&
                          (h > 2.0f) && (h < 10000.0f) && fin;
                float off = (float)am * 10000.0f;
                float x1 = cx - w * 0.5f, y1 = cy - h * 0.5f;
                float x2 = cx + w * 0.5f, y2 = cy + h * 0.5f;
                float* sp = sel + ((long long)b * KSEL + r) * 8;
                sp[0] = x1 + off; sp[1] = y1; sp[2] = x2 + off; sp[3] = y2;
                sp[4] = conf; sp[5] = mx; sp[6] = (float)am; sp[7] = ok ? 1.0f : 0.0f;
            }
        }
    }
}

// ---------------- K4: 512x512 iou>thres bitmatrix, TRANSPOSED [b][w][i], 256 blocks ----------------
__global__ __launch_bounds__(256) void k4_iou(const float* __restrict__ sel, u64* __restrict__ matT) {
    int b = blockIdx.x >> 4;
    int t = ((blockIdx.x & 15) << 8) + threadIdx.x;
    int w = t >> 9;             // uniform per block
    int i = t & (KSEL - 1);
    __shared__ float BX[KSEL * 4]; // 8KB
    const float4* S4 = (const float4*)(sel + (long long)b * KSEL * 8);
    float4* B4 = (float4*)BX;
    for (int j = threadIdx.x; j < KSEL; j += 256) B4[j] = S4[j * 2];
    __syncthreads();
    float x1 = BX[i * 4 + 0], y1 = BX[i * 4 + 1], x2 = BX[i * 4 + 2], y2 = BX[i * 4 + 3];
    float a1 = __fmul_rn(__fsub_rn(x2, x1), __fsub_rn(y2, y1));
    u64 bits = 0;
    int j0 = w * 64;
    const float4* BB = (const float4*)BX;
    for (int jj = 0; jj < 64; jj++) {
        float4 bj = BB[j0 + jj]; // broadcast: block shares w
        float ix = fmaxf(__fsub_rn(fminf(x2, bj.z), fmaxf(x1, bj.x)), 0.0f);
        float iy = fmaxf(__fsub_rn(fminf(y2, bj.w), fmaxf(y1, bj.y)), 0.0f);
        float inter = __fmul_rn(ix, iy);
        float a2 = __fmul_rn(__fsub_rn(bj.z, bj.x), __fsub_rn(bj.w, bj.y));
        float denom = __fadd_rn(__fsub_rn(__fadd_rn(a1, a2), inter), 1e-9f);
        float iou = __fdiv_rn(inter, denom);
        if (iou > NMS_T) bits |= (1ull << jj);
    }
    matT[((long long)b * 8 + w) * KSEL + i] = bits; // coalesced
}

// ---------------- K5: chunked scalar keep-scan + parallel merge + output (1024 thr) ----------------
__global__ __launch_bounds__(1024) void k5_nms(const float* __restrict__ sel,
                                               const u64* __restrict__ matT,
                                               float* __restrict__ out) {
    int b = blockIdx.x;
    int tid = threadIdx.x;
    int lane = tid & 63;
    int wv = tid >> 6;
    __shared__ float S[KSEL * 8];        // 16KB
    __shared__ u64 MT[8 * KSEL];         // 32KB, [w][i]
    __shared__ float MG[KSEL * 4];       // 8KB
    __shared__ unsigned short TGT[KSEL]; // 1KB
    __shared__ u64 sh_keep[8], sh_ok[8];
    const float4* gs = (const float4*)(sel + (long long)b * KSEL * 8);
    float4* s4 = (float4*)S;
    for (int i = tid; i < KSEL * 2; i += 1024) s4[i] = gs[i];
    const ulonglong2* gm2 = (const ulonglong2*)(matT + (long long)b * 8 * KSEL);
    ulonglong2* m2 = (ulonglong2*)MT;
    for (int i = tid; i < 4 * KSEL; i += 1024) m2[i] = gm2[i];
    __syncthreads();

    if (wv == 0) {
        u32 a_bits = 0; // bit w = column (w*64+lane) alive
        #pragma unroll
        for (int w = 0; w < 8; w++)
            if (S[(w * 64 + lane) * 8 + 7] > 0.5f) a_bits |= 1u << w;
        #pragma unroll
        for (int w = 0; w < 8; w++) {
            u64 ow = __ballot((a_bits >> w) & 1u);
            if (lane == 0) sh_ok[w] = ow;
        }
        #pragma unroll 1
        for (int c = 0; c < 8; c++) {
            u64 cross[8];
            #pragma unroll
            for (int w = 0; w < 8; w++) cross[w] = MT[c * KSEL + w * 64 + lane];
            u64 intra = MT[c * KSEL + c * 64 + lane];
            u64 aliveC = __ballot((a_bits >> c) & 1u);
            u32 ilo = (u32)intra, ihi = (u32)(intra >> 32);
            u64 keptC = 0;
            #pragma unroll
            for (int m = 0; m < 64; m++) { // symmetric: row m == lane m's column word
                u32 rl = __builtin_amdgcn_readlane(ilo, m);
                u32 rh = __builtin_amdgcn_readlane(ihi, m);
                u64 rowm = ((u64)rh << 32) | rl;
                u64 take = (aliveC >> m) & 1ull;
                u64 msk = (u64)0 - take;
                keptC |= take << m;
                aliveC &= ~(rowm & msk);
            }
            if (lane == 0) sh_keep[c] = keptC;
            #pragma unroll
            for (int w = 0; w < 8; w++)
                if (cross[w] & keptC) a_bits &= ~(1u << w);
        }
    }
    __syncthreads();
    u64 keepW[8], okW[8];
    #pragma unroll
    for (int w = 0; w < 8; w++) { keepW[w] = sh_keep[w]; okW[w] = sh_ok[w]; }

    // merge target per column (M symmetric)
    for (int j = tid; j < KSEL; j += 1024) {
        int r = j >> 6, ln = j & 63;
        int tgt = 0xffff;
        if ((okW[r] >> ln) & 1ull) {
            #pragma unroll
            for (int w = 7; w >= 0; w--) {
                u64 m = MT[w * KSEL + j] & keepW[w];
                if (m) tgt = w * 64 + (int)__builtin_ctzll(m);
            }
        }
        TGT[j] = (unsigned short)tgt;
    }
    __syncthreads();

    // weighted merge per kept row, ascending-j order
    for (int k = tid; k < KSEL; k += 1024) {
        int r = k >> 6, ln = k & 63;
        if ((keepW[r] >> ln) & 1ull) {
            float s0 = 0.f, s1 = 0.f, s2 = 0.f, s3 = 0.f, sw = 0.f;
            #pragma unroll 1
            for (int w = 0; w < 8; w++) {
                u64 m = MT[w * KSEL + k] & okW[w];
                while (m) {
                    int j = w * 64 + (int)__builtin_ctzll(m);
                    m &= m - 1;
                    if (TGT[j] == (unsigned short)k) {
                        float c = S[j * 8 + 4];
                        s0 += c * S[j * 8 + 0]; s1 += c * S[j * 8 + 1];
                        s2 += c * S[j * 8 + 2]; s3 += c * S[j * 8 + 3];
                        sw += c;
                    }
                }
            }
            float d = sw + 1e-12f;
            MG[k * 4 + 0] = s0 / d; MG[k * 4 + 1] = s1 / d;
            MG[k * 4 + 2] = s2 / d; MG[k * 4 + 3] = s3 / d;
        }
    }
    __syncthreads();

    // output: compact kept rows in order, zero tail
    int nk = 0;
    #pragma unroll
    for (int w = 0; w < 8; w++) nk += __popcll(keepW[w]);
    float* ob = out + (long long)b * KSEL * 7;
    for (int i = tid; i < KSEL; i += 1024) {
        int wi = i >> 6, bi = i & 63;
        if ((keepW[wi] >> bi) & 1ull) {
            int rank = 0;
            for (int w = 0; w < wi; w++) rank += __popcll(keepW[w]);
            rank += __popcll(keepW[wi] & ((1ull << bi) - 1ull));
            float off = S[i * 8 + 6] * 10000.0f;
            float* o = ob + rank * 7;
            o[0] = MG[i * 4 + 0] - off; o[1] = MG[i * 4 + 1];
            o[2] = MG[i * 4 + 2] - off; o[3] = MG[i * 4 + 3];
            o[4] = S[i * 8 + 4]; o[5] = S[i * 8 + 5]; o[6] = S[i * 8 + 6];
        }
    }
    for (int p = nk + tid; p < KSEL; p += 1024) {
        float* o = ob + p * 7;
        #pragma unroll
        for (int c = 0; c < 7; c++) o[c] = 0.0f;
    }
}

extern "C" void kernel_launch(void* const* d_in, const int* in_sizes, int n_in,
                              void* d_out, int out_size, void* d_ws, size_t ws_size,
                              hipStream_t stream) {
    const float* pred = (const float*)d_in[0];
    float* out = (float*)d_out;
    int total = in_sizes[0];
    int N = total / (BN * ROWF); // 22743
    int totalRows = BN * N;

    char* ws = (char*)d_ws;
    size_t o = 0;
    u32* keys = (u32*)(ws + o);    o += (size_t)totalRows * 4;
    float* sel = (float*)(ws + o); o += (size_t)BN * KSEL * 8 * 4;
    u64* matT = (u64*)(ws + o);    o += (size_t)BN * KSEL * 8 * 8;
    u64* tiesG = (u64*)(ws + o);   o += (size_t)BN * N * 8;
    (void)ws_size;

    k1_keys<<<(totalRows + 127) / 128, 512, 0, stream>>>(pred, keys, totalRows);
    kM<<<BN, 1024, 0, stream>>>(pred, keys, tiesG, sel, N);
    k4_iou<<<BN * 16, 256, 0, stream>>>(sel, matT);
    k5_nms<<<BN, 1024, 0, stream>>>(sel, matT, out);
}